// Round 9
// baseline (216.477 us; speedup 1.0000x reference)
//
#include <hip/hip_runtime.h>
#include <float.h>

#define HW    4096      // H*W
#define NC    64        // channels / latent dim
#define NK    1024      // codebook entries
#define NB    32        // batch
#define NPIX  (NB*HW)   // 131072 pixels
#define TOTAL (NPIX*NC) // 8388608 output elements of z_q
#define PPB   256       // pixels per block (64 per wave, 4 MFMA B-sets)

// bf16 hi/lo split score error bound ~1.4e-3 worst case; MARGIN 8e-3 gives
// >4x safety (validated rounds 4-8, absmax 0). gap2<MARGIN (incl. any exact
// fp32 tie) -> cooperative exact fp64 full rescan (~0.13%/pixel).
#define MARGIN 8e-3f

typedef __attribute__((ext_vector_type(8))) short short8;   // 8 bf16 (4 VGPRs)
typedef __attribute__((ext_vector_type(4))) float floatx4;  // MFMA acc

__device__ __forceinline__ unsigned short f2bf(float f) {   // fp32 -> bf16 RNE
    unsigned u = __float_as_uint(f);
    u += 0x7FFFu + ((u >> 16) & 1u);
    return (unsigned short)(u >> 16);
}
__device__ __forceinline__ float bf2f(unsigned short h) {
    return __uint_as_float(((unsigned)h) << 16);
}

// Prep: blocks 0..63 do the element-parallel bf16 hi/lo split with fully
// coalesced 16B-in / 8B-out accesses (the old per-code layout issued 128
// uncoalesced 2B stores per thread -> tens of us). Blocks 64..67 compute
// fp64-accurate cnorm (independent of the split - reads cb directly).
__global__ void vq_prep_kernel(const float* __restrict__ cb,
                               float* __restrict__ cnorm,
                               unsigned short* __restrict__ cb_hi,
                               unsigned short* __restrict__ cb_lo,
                               float* __restrict__ loss_out) {
    const int b = blockIdx.x;
    if (b < 64) {
        const int i = b * 256 + threadIdx.x;     // float4 index, 16384 total
        if (i == 0) loss_out[0] = 0.0f;
        float4 v = ((const float4*)cb)[i];
        unsigned short h0 = f2bf(v.x), h1 = f2bf(v.y),
                       h2 = f2bf(v.z), h3 = f2bf(v.w);
        unsigned short l0 = f2bf(v.x - bf2f(h0)), l1 = f2bf(v.y - bf2f(h1)),
                       l2 = f2bf(v.z - bf2f(h2)), l3 = f2bf(v.w - bf2f(h3));
        uint2 ph = make_uint2((unsigned)h0 | ((unsigned)h1 << 16),
                              (unsigned)h2 | ((unsigned)h3 << 16));
        uint2 pl = make_uint2((unsigned)l0 | ((unsigned)l1 << 16),
                              (unsigned)l2 | ((unsigned)l3 << 16));
        ((uint2*)cb_hi)[i] = ph;                 // coalesced 8B stores
        ((uint2*)cb_lo)[i] = pl;
    } else {
        const int k = (b - 64) * 256 + threadIdx.x;  // 0..1023
        const float4* r4 = (const float4*)(cb + (size_t)k * NC);
        double s = 0.0;
        #pragma unroll
        for (int j = 0; j < 16; ++j) {
            float4 v = r4[j];
            s = fma((double)v.x, (double)v.x, s);
            s = fma((double)v.y, (double)v.y, s);
            s = fma((double)v.z, (double)v.z, s);
            s = fma((double)v.w, (double)v.w, s);
        }
        cnorm[k] = (float)s;
    }
}

// Main: block = 256 threads / 4 waves / 256 pixels (64 per wave, 4 B-sets).
// z is staged in TWO 32-channel rounds through a 32 KB LDS window (fragments
// extracted after each round), then the A-tile double buffer aliases that
// window -> static LDS ~39 KB -> 4 blocks/CU -> barrier phases of the four
// co-resident blocks interleave and keep the SIMDs fed (the R8 lesson:
// 2 blocks/CU left 55% of issue slots idle).
__global__ __launch_bounds__(256, 4) void vq_mfma_kernel(
        const float* __restrict__ z,
        const float* __restrict__ cb,
        const unsigned short* __restrict__ cb_hi,
        const unsigned short* __restrict__ cb_lo,
        const float* __restrict__ cnorm,
        float* __restrict__ zq,
        float* __restrict__ loss_out) {
    // 32 KB window: phase 1 = zh/zl staging (2 rounds), phase 2 = A dbuf.
    __shared__ alignas(16) char smem[32768];
    __shared__ alignas(16) float cn_lds[NK];   // 4 KB; rescan scratch aliases
    __shared__ int   finidx[PPB];
    __shared__ int   flags[PPB];
    __shared__ float redf[4];

    const int tid = threadIdx.x;
    const int g0  = blockIdx.x * PPB;
    const int bb  = g0 >> 12;
    const int pp0 = g0 & 4095;
    const float* zbase = z  + (size_t)bb * (NC * HW) + pp0;
    float*      zqbase = zq + (size_t)bb * (NC * HW) + pp0;

    // ---- stage cnorm -> LDS ----
    ((float4*)cn_lds)[tid] = ((const float4*)cnorm)[tid];

    const int lane = tid & 63;
    const int w    = tid >> 6;
    const int q    = lane >> 4;
    const int pcol = lane & 15;

    // ---- phase 1: z -> bf16 hi/lo of (-2*z), 2 rounds of 32 channels ----
    unsigned short (*zh)[PPB] = (unsigned short(*)[PPB])smem;           // [32][256]
    unsigned short (*zl)[PPB] = (unsigned short(*)[PPB])(smem + 16384); // [32][256]

    short8 Bh[2][4], Bl[2][4];   // [k-step r][pixel set j]
    #pragma unroll
    for (int r = 0; r < 2; ++r) {
        const int px4 = (tid & 63) * 4;      // 0..252
        const int c0  = tid >> 6;            // 0..3
        #pragma unroll
        for (int it = 0; it < 8; ++it) {
            const int c = it * 4 + c0;       // 0..31 local channel
            float4 v = *(const float4*)(zbase + (size_t)(r * 32 + c) * HW + px4);
            v.x *= -2.0f; v.y *= -2.0f; v.z *= -2.0f; v.w *= -2.0f;
            unsigned short h0 = f2bf(v.x), h1 = f2bf(v.y),
                           h2 = f2bf(v.z), h3 = f2bf(v.w);
            unsigned short l0 = f2bf(v.x - bf2f(h0)), l1 = f2bf(v.y - bf2f(h1)),
                           l2 = f2bf(v.z - bf2f(h2)), l3 = f2bf(v.w - bf2f(h3));
            uint2 ph = make_uint2((unsigned)h0 | ((unsigned)h1 << 16),
                                  (unsigned)h2 | ((unsigned)h3 << 16));
            uint2 pl = make_uint2((unsigned)l0 | ((unsigned)l1 << 16),
                                  (unsigned)l2 | ((unsigned)l3 << 16));
            *(uint2*)&zh[c][px4] = ph;
            *(uint2*)&zl[c][px4] = pl;
        }
        __syncthreads();
        #pragma unroll
        for (int j = 0; j < 4; ++j) {
            const int px = w * 64 + j * 16 + pcol;
            #pragma unroll
            for (int t = 0; t < 8; ++t) {
                Bh[r][j][t] = (short)zh[q * 8 + t][px];
                Bl[r][j][t] = (short)zl[q * 8 + t][px];
            }
        }
        __syncthreads();   // window reusable (next round / A dbuf)
    }

    // ---- phase 2: sweep 64 tiles, A staged via XOR-swizzled LDS dbuf ----
    // abuf layout (uint4 units): [buf(2)][part(2)][row(16)][chunk^(row&7)(8)]
    // Writes: 8 consecutive lanes cover one 128B row permuted -> each bank
    // once. Reads: quad q's 16 lanes spread over all 8 bank-groups, 2 each
    // (free 2-way).
    uint4* abuf = (uint4*)smem;
    const int spart = tid >> 7;            // 0 = hi, 1 = lo
    const int sidx  = tid & 127;           // row*8 + chunk (global order)
    const int srow  = sidx >> 3;
    const int schk  = sidx & 7;
    const int ldst  = spart * 128 + srow * 8 + (schk ^ (srow & 7));
    const char* gsrc = (spart == 0 ? (const char*)cb_hi : (const char*)cb_lo)
                       + (size_t)sidx * 16;

    // per-lane fixed read offsets (uint4 units within a part)
    const int ridx0 = pcol * 8 + (q ^ (pcol & 7));        // chunk q
    const int ridx1 = pcol * 8 + ((4 + q) ^ (pcol & 7));  // chunk 4+q

    uint4 sreg = *(const uint4*)(gsrc);            // tile 0
    abuf[ldst] = sreg;                             // -> buf 0
    sreg = *(const uint4*)(gsrc + 2048);           // tile 1
    __syncthreads();                               // buf0 visible

    float B1[4] = {FLT_MAX, FLT_MAX, FLT_MAX, FLT_MAX};
    float B2[4] = {FLT_MAX, FLT_MAX, FLT_MAX, FLT_MAX};
    int   I1[4] = {0, 0, 0, 0};

    #pragma unroll 2
    for (int tile = 0; tile < 64; ++tile) {
        if (tile < 63) abuf[((tile + 1) & 1) * 256 + ldst] = sreg;
        if (tile < 62) sreg = *(const uint4*)(gsrc + (size_t)(tile + 2) * 2048);

        const short8* A = (const short8*)smem + (tile & 1) * 256;
        short8 ah0 = A[ridx0];
        short8 ah1 = A[ridx1];
        short8 al0 = A[128 + ridx0];
        short8 al1 = A[128 + ridx1];

        const floatx4 cn4 = *(const floatx4*)&cn_lds[tile * 16 + q * 4];
        const int kb = tile * 16 + q * 4;
        #pragma unroll
        for (int j = 0; j < 4; ++j) {
            // score = cn + (-2z).e :  e_hi*z_hi + e_hi*z_lo + e_lo*z_hi
            floatx4 a0 = __builtin_amdgcn_mfma_f32_16x16x32_bf16(ah0, Bh[0][j], cn4, 0, 0, 0);
            floatx4 a1 = {0.f, 0.f, 0.f, 0.f};
            a1 = __builtin_amdgcn_mfma_f32_16x16x32_bf16(ah1, Bh[1][j], a1, 0, 0, 0);
            a0 = __builtin_amdgcn_mfma_f32_16x16x32_bf16(ah0, Bl[0][j], a0, 0, 0, 0);
            a1 = __builtin_amdgcn_mfma_f32_16x16x32_bf16(ah1, Bl[1][j], a1, 0, 0, 0);
            a0 = __builtin_amdgcn_mfma_f32_16x16x32_bf16(al0, Bh[0][j], a0, 0, 0, 0);
            a1 = __builtin_amdgcn_mfma_f32_16x16x32_bf16(al1, Bh[1][j], a1, 0, 0, 0);

            // C/D layout: code row = q*4+reg, pixel col = lane&15 (verified)
            #pragma unroll
            for (int i = 0; i < 4; ++i) {
                float s = a0[i] + a1[i];
                bool lt = s < B1[j];                 // strict: first min wins
                I1[j] = lt ? (kb + i) : I1[j];
                B2[j] = __builtin_amdgcn_fmed3f(s, B1[j], B2[j]);
                B1[j] = fminf(s, B1[j]);
            }
        }
        __syncthreads();   // next buffer fully written before anyone reads it
    }

    // ---- merge top-2 across the 4 lanes sharing each pixel (xor 16,32) ----
    #pragma unroll
    for (int j = 0; j < 4; ++j) {
        float b1 = B1[j], b2 = B2[j];
        int i1 = I1[j];
        #pragma unroll
        for (int d = 16; d <= 32; d <<= 1) {
            float ob1 = __shfl_xor(b1, d);
            float ob2 = __shfl_xor(b2, d);
            int   oi1 = __shfl_xor(i1, d);
            // second-smallest of {b1,b2,ob1,ob2}; equal b1s -> gap 0 -> rescan
            float nb2 = fminf(fmaxf(b1, ob1), fminf(b2, ob2));
            bool lt = (ob1 < b1) || (ob1 == b1 && oi1 < i1);
            b1 = lt ? ob1 : b1;
            i1 = lt ? oi1 : i1;
            b2 = nb2;
        }
        if (q == 0) {
            const int px = w * 64 + j * 16 + pcol;
            finidx[px] = i1;
            flags[px]  = (b2 - b1 < MARGIN) ? 1 : 0;
        }
    }
    int myflag = 0;
    __syncthreads();
    myflag = flags[tid];
    const int nflag = __syncthreads_count(myflag);

    // ---- rare cooperative exact fp64 rescan (scratch aliases cn_lds) ----
    if (nflag > 0) {
        double* red_s = reinterpret_cast<double*>(cn_lds);       // 2 KB
        int*    red_i = reinterpret_cast<int*>(cn_lds + 512);    // 1 KB
        for (int p = 0; p < PPB; ++p) {
            if (flags[p]) {
                const float* zp = zbase + p;
                double bd = 1.0e300; int bi = 0;
                #pragma unroll 1
                for (int r = 0; r < 4; ++r) {
                    const int k = tid * 4 + r;
                    const float* rowp = cb + (size_t)k * NC;
                    double s = 0.0;
                    for (int c = 0; c < NC; ++c) {
                        double t = (double)zp[(size_t)c * HW] - (double)rowp[c];
                        s = fma(t, t, s);
                    }
                    if (s < bd) { bd = s; bi = k; }  // k increasing: first min
                }
                red_s[tid] = bd; red_i[tid] = bi;
                __syncthreads();
                if (tid < 64) {
                    double m = red_s[tid]; int mi = red_i[tid];
                    #pragma unroll
                    for (int t = 1; t < 4; ++t) {
                        double om = red_s[tid + 64 * t];
                        int    oi = red_i[tid + 64 * t];
                        if (om < m || (om == m && oi < mi)) { m = om; mi = oi; }
                    }
                    #pragma unroll
                    for (int off = 32; off > 0; off >>= 1) {
                        double om = __shfl_down(m, off);
                        int    oi = __shfl_down(mi, off);
                        if (om < m || (om == m && oi < mi)) { m = om; mi = oi; }
                    }
                    if (tid == 0) finidx[p] = mi;
                }
                __syncthreads();
            }
        }
        __syncthreads();
    }

    // ---- epilogue: gather exact fp32 code row -> z_q, loss SSE ----
    // 1 thread per pixel, 64 channels.
    {
        const int p  = tid;
        const int fi = finidx[p];
        const float4* crow4 = (const float4*)(cb + (size_t)fi * NC);
        float sse = 0.f;
        #pragma unroll
        for (int j = 0; j < 16; ++j) {
            const float4 qv = crow4[j];
            const size_t c0 = (size_t)(4 * j) * HW + p;
            const float z0 = zbase[c0];
            const float z1 = zbase[c0 + HW];
            const float z2 = zbase[c0 + 2 * (size_t)HW];
            const float z3 = zbase[c0 + 3 * (size_t)HW];
            zqbase[c0]                  = qv.x;   // coalesced across threads
            zqbase[c0 + HW]             = qv.y;
            zqbase[c0 + 2 * (size_t)HW] = qv.z;
            zqbase[c0 + 3 * (size_t)HW] = qv.w;
            float t0 = qv.x - z0, t1 = qv.y - z1, t2 = qv.z - z2, t3 = qv.w - z3;
            sse = fmaf(t0, t0, sse);
            sse = fmaf(t1, t1, sse);
            sse = fmaf(t2, t2, sse);
            sse = fmaf(t3, t3, sse);
        }
        #pragma unroll
        for (int off = 32; off > 0; off >>= 1) sse += __shfl_down(sse, off);
        if ((tid & 63) == 0) redf[tid >> 6] = sse;
        __syncthreads();
        if (tid == 0)
            atomicAdd(loss_out, (redf[0] + redf[1] + redf[2] + redf[3]) *
                                (1.25f / (float)TOTAL));
    }
}

extern "C" void kernel_launch(void* const* d_in, const int* in_sizes, int n_in,
                              void* d_out, int out_size, void* d_ws, size_t ws_size,
                              hipStream_t stream) {
    const float* z  = (const float*)d_in[0];   // [32, 64, 64, 64] fp32
    const float* cb = (const float*)d_in[1];   // [1024, 64] fp32
    float* out      = (float*)d_out;           // z_q ++ loss
    float* zqp      = out;
    float* loss     = out + TOTAL;

    // ws: cnorm fp32[1024] | cb_hi bf16[1024*64] | cb_lo bf16[1024*64]
    float* cnorm          = (float*)d_ws;
    unsigned short* cb_hi = (unsigned short*)((char*)d_ws + 4096);
    unsigned short* cb_lo = (unsigned short*)((char*)d_ws + 4096 + NK * NC * 2);

    vq_prep_kernel<<<68, 256, 0, stream>>>(cb, cnorm, cb_hi, cb_lo, loss);
    vq_mfma_kernel<<<NPIX / PPB, 256, 0, stream>>>(z, cb, cb_hi, cb_lo, cnorm,
                                                   zqp, loss);
}

// Round 10
// 176.552 us; speedup vs baseline: 1.2261x; 1.2261x over previous
//
#include <hip/hip_runtime.h>
#include <float.h>

#define HW    4096      // H*W
#define NC    64        // channels / latent dim
#define NK    1024      // codebook entries
#define NB    32        // batch
#define NPIX  (NB*HW)   // 131072 pixels
#define TOTAL (NPIX*NC) // 8388608 output elements of z_q
#define PPB   128       // pixels per block (32 per wave, 2 MFMA B-sets)

// bf16 hi/lo split score error bound ~1.4e-3 worst case; MARGIN 8e-3 gives
// >4x safety (validated rounds 4-9, absmax 0). gap2<MARGIN (incl. any exact
// fp32 tie) -> cooperative exact fp64 full rescan (~0.13%/pixel).
#define MARGIN 8e-3f

typedef __attribute__((ext_vector_type(8))) short short8;   // 8 bf16 (4 VGPRs)
typedef __attribute__((ext_vector_type(4))) float floatx4;  // MFMA acc

__device__ __forceinline__ unsigned short f2bf(float f) {   // fp32 -> bf16 RNE
    unsigned u = __float_as_uint(f);
    u += 0x7FFFu + ((u >> 16) & 1u);
    return (unsigned short)(u >> 16);
}
__device__ __forceinline__ float bf2f(unsigned short h) {
    return __uint_as_float(((unsigned)h) << 16);
}

// Prep: blocks 0..63 element-parallel bf16 hi/lo split, fully coalesced
// 16B-in / 8B-out. Blocks 64..67: fp64-accurate cnorm.
__global__ void vq_prep_kernel(const float* __restrict__ cb,
                               float* __restrict__ cnorm,
                               unsigned short* __restrict__ cb_hi,
                               unsigned short* __restrict__ cb_lo,
                               float* __restrict__ loss_out) {
    const int b = blockIdx.x;
    if (b < 64) {
        const int i = b * 256 + threadIdx.x;     // float4 index, 16384 total
        if (i == 0) loss_out[0] = 0.0f;
        float4 v = ((const float4*)cb)[i];
        unsigned short h0 = f2bf(v.x), h1 = f2bf(v.y),
                       h2 = f2bf(v.z), h3 = f2bf(v.w);
        unsigned short l0 = f2bf(v.x - bf2f(h0)), l1 = f2bf(v.y - bf2f(h1)),
                       l2 = f2bf(v.z - bf2f(h2)), l3 = f2bf(v.w - bf2f(h3));
        uint2 ph = make_uint2((unsigned)h0 | ((unsigned)h1 << 16),
                              (unsigned)h2 | ((unsigned)h3 << 16));
        uint2 pl = make_uint2((unsigned)l0 | ((unsigned)l1 << 16),
                              (unsigned)l2 | ((unsigned)l3 << 16));
        ((uint2*)cb_hi)[i] = ph;                 // coalesced 8B stores
        ((uint2*)cb_lo)[i] = pl;
    } else {
        const int k = (b - 64) * 256 + threadIdx.x;  // 0..1023
        const float4* r4 = (const float4*)(cb + (size_t)k * NC);
        double s = 0.0;
        #pragma unroll
        for (int j = 0; j < 16; ++j) {
            float4 v = r4[j];
            s = fma((double)v.x, (double)v.x, s);
            s = fma((double)v.y, (double)v.y, s);
            s = fma((double)v.z, (double)v.z, s);
            s = fma((double)v.w, (double)v.w, s);
        }
        cnorm[k] = (float)s;
    }
}

// Main: block = 256 threads / 4 waves / 128 pixels (32 per wave, 2 B-sets).
// NO z-staging LDS: each lane loads its 32 strided z values straight from
// global (one-time, 4x64B sectors per instr) and converts in-register ->
// LDS is only the XOR-swizzled A-tile double buffer (8 KB) + cnorm (4 KB),
// ~13.5 KB total -> 4 blocks/CU without spill pressure (the R9 lesson).
__global__ __launch_bounds__(256, 4) void vq_mfma_kernel(
        const float* __restrict__ z,
        const float* __restrict__ cb,
        const unsigned short* __restrict__ cb_hi,
        const unsigned short* __restrict__ cb_lo,
        const float* __restrict__ cnorm,
        float* __restrict__ zq,
        float* __restrict__ loss_out) {
    __shared__ alignas(16) uint4 abuf[512];    // 8 KB A-tile double buffer
    __shared__ alignas(16) float cn_lds[NK];   // 4 KB; rescan scratch aliases
    __shared__ int   finidx[PPB];
    __shared__ int   flags[PPB];
    __shared__ float redf[4];

    const int tid = threadIdx.x;
    const int g0  = blockIdx.x * PPB;
    const int bb  = g0 >> 12;
    const int pp0 = g0 & 4095;
    const float* zbase = z  + (size_t)bb * (NC * HW) + pp0;
    float*      zqbase = zq + (size_t)bb * (NC * HW) + pp0;

    // ---- stage cnorm -> LDS ----
    ((float4*)cn_lds)[tid] = ((const float4*)cnorm)[tid];

    const int lane = tid & 63;
    const int w    = tid >> 6;
    const int q    = lane >> 4;
    const int pcol = lane & 15;

    // ---- B fragments straight from global: 32 strided floats per lane ----
    // B[k][n]: n = this lane's pixel, k = q*8+t (kstep 0) / 32+q*8+t (kstep 1)
    float zraw[2][2][8];                 // [kstep][pixel set][t]
    #pragma unroll
    for (int ks = 0; ks < 2; ++ks)
        #pragma unroll
        for (int j = 0; j < 2; ++j)
            #pragma unroll
            for (int t = 0; t < 8; ++t)
                zraw[ks][j][t] = zbase[(size_t)(ks * 32 + q * 8 + t) * HW
                                       + (w * 32 + j * 16 + pcol)];
    short8 Bh[2][2], Bl[2][2];
    #pragma unroll
    for (int ks = 0; ks < 2; ++ks)
        #pragma unroll
        for (int j = 0; j < 2; ++j)
            #pragma unroll
            for (int t = 0; t < 8; ++t) {
                float v = -2.0f * zraw[ks][j][t];
                unsigned short h = f2bf(v);
                unsigned short l = f2bf(v - bf2f(h));
                Bh[ks][j][t] = (short)h;
                Bl[ks][j][t] = (short)l;
            }

    // ---- sweep 64 code tiles, A staged via XOR-swizzled LDS dbuf ----
    // abuf layout (uint4 units): [buf(2)][part(2)][row(16)][chunk^(row&7)(8)]
    // Writes: 8 consecutive lanes cover one 128B row permuted -> each bank
    // once. Reads: quad q's 16 lanes spread over all 8 bank-groups (free
    // 2-way). Verified conflict-free in R8 (5.2e5 vs R7's 1.5e7).
    const int spart = tid >> 7;            // 0 = hi, 1 = lo
    const int sidx  = tid & 127;           // row*8 + chunk (global order)
    const int srow  = sidx >> 3;
    const int schk  = sidx & 7;
    const int ldst  = spart * 128 + srow * 8 + (schk ^ (srow & 7));
    const char* gsrc = (spart == 0 ? (const char*)cb_hi : (const char*)cb_lo)
                       + (size_t)sidx * 16;

    // per-lane fixed read offsets (uint4 units within a part)
    const int ridx0 = pcol * 8 + (q ^ (pcol & 7));        // chunk q
    const int ridx1 = pcol * 8 + ((4 + q) ^ (pcol & 7));  // chunk 4+q

    uint4 sreg = *(const uint4*)(gsrc);            // tile 0
    abuf[ldst] = sreg;                             // -> buf 0
    sreg = *(const uint4*)(gsrc + 2048);           // tile 1
    __syncthreads();                               // buf0 visible

    float B1[2] = {FLT_MAX, FLT_MAX};
    float B2[2] = {FLT_MAX, FLT_MAX};
    int   I1[2] = {0, 0};

    #pragma unroll 2
    for (int tile = 0; tile < 64; ++tile) {
        if (tile < 63) abuf[((tile + 1) & 1) * 256 + ldst] = sreg;
        if (tile < 62) sreg = *(const uint4*)(gsrc + (size_t)(tile + 2) * 2048);

        const short8* A = (const short8*)abuf + (tile & 1) * 256;
        short8 ah0 = A[ridx0];
        short8 ah1 = A[ridx1];
        short8 al0 = A[128 + ridx0];
        short8 al1 = A[128 + ridx1];

        const floatx4 cn4 = *(const floatx4*)&cn_lds[tile * 16 + q * 4];
        const int kb = tile * 16 + q * 4;
        #pragma unroll
        for (int j = 0; j < 2; ++j) {
            // score = cn + (-2z).e :  e_hi*z_hi + e_hi*z_lo + e_lo*z_hi
            floatx4 a0 = __builtin_amdgcn_mfma_f32_16x16x32_bf16(ah0, Bh[0][j], cn4, 0, 0, 0);
            floatx4 a1 = {0.f, 0.f, 0.f, 0.f};
            a1 = __builtin_amdgcn_mfma_f32_16x16x32_bf16(ah1, Bh[1][j], a1, 0, 0, 0);
            a0 = __builtin_amdgcn_mfma_f32_16x16x32_bf16(ah0, Bl[0][j], a0, 0, 0, 0);
            a1 = __builtin_amdgcn_mfma_f32_16x16x32_bf16(ah1, Bl[1][j], a1, 0, 0, 0);
            a0 = __builtin_amdgcn_mfma_f32_16x16x32_bf16(al0, Bh[0][j], a0, 0, 0, 0);
            a1 = __builtin_amdgcn_mfma_f32_16x16x32_bf16(al1, Bh[1][j], a1, 0, 0, 0);

            // C/D layout: code row = q*4+reg, pixel col = lane&15 (verified)
            #pragma unroll
            for (int i = 0; i < 4; ++i) {
                float s = a0[i] + a1[i];
                bool lt = s < B1[j];                 // strict: first min wins
                I1[j] = lt ? (kb + i) : I1[j];
                B2[j] = __builtin_amdgcn_fmed3f(s, B1[j], B2[j]);
                B1[j] = fminf(s, B1[j]);
            }
        }
        __syncthreads();   // next buffer fully written before anyone reads it
    }

    // ---- merge top-2 across the 4 lanes sharing each pixel (xor 16,32) ----
    #pragma unroll
    for (int j = 0; j < 2; ++j) {
        float b1 = B1[j], b2 = B2[j];
        int i1 = I1[j];
        #pragma unroll
        for (int d = 16; d <= 32; d <<= 1) {
            float ob1 = __shfl_xor(b1, d);
            float ob2 = __shfl_xor(b2, d);
            int   oi1 = __shfl_xor(i1, d);
            // second-smallest of {b1,b2,ob1,ob2}; equal b1s -> gap 0 -> rescan
            float nb2 = fminf(fmaxf(b1, ob1), fminf(b2, ob2));
            bool lt = (ob1 < b1) || (ob1 == b1 && oi1 < i1);
            b1 = lt ? ob1 : b1;
            i1 = lt ? oi1 : i1;
            b2 = nb2;
        }
        if (q == 0) {
            const int px = w * 32 + j * 16 + pcol;
            finidx[px] = i1;
            flags[px]  = (b2 - b1 < MARGIN) ? 1 : 0;
        }
    }
    int myflag = 0;
    __syncthreads();
    if (tid < PPB) myflag = flags[tid];
    const int nflag = __syncthreads_count(myflag);

    // ---- rare cooperative exact fp64 rescan (scratch aliases cn_lds) ----
    if (nflag > 0) {
        double* red_s = reinterpret_cast<double*>(cn_lds);       // 2 KB
        int*    red_i = reinterpret_cast<int*>(cn_lds + 512);    // 1 KB
        for (int p = 0; p < PPB; ++p) {
            if (flags[p]) {
                const float* zp = zbase + p;
                double bd = 1.0e300; int bi = 0;
                #pragma unroll 1
                for (int r = 0; r < 4; ++r) {
                    const int k = tid * 4 + r;
                    const float* rowp = cb + (size_t)k * NC;
                    double s = 0.0;
                    for (int c = 0; c < NC; ++c) {
                        double t = (double)zp[(size_t)c * HW] - (double)rowp[c];
                        s = fma(t, t, s);
                    }
                    if (s < bd) { bd = s; bi = k; }  // k increasing: first min
                }
                red_s[tid] = bd; red_i[tid] = bi;
                __syncthreads();
                if (tid < 64) {
                    double m = red_s[tid]; int mi = red_i[tid];
                    #pragma unroll
                    for (int t = 1; t < 4; ++t) {
                        double om = red_s[tid + 64 * t];
                        int    oi = red_i[tid + 64 * t];
                        if (om < m || (om == m && oi < mi)) { m = om; mi = oi; }
                    }
                    #pragma unroll
                    for (int off = 32; off > 0; off >>= 1) {
                        double om = __shfl_down(m, off);
                        int    oi = __shfl_down(mi, off);
                        if (om < m || (om == m && oi < mi)) { m = om; mi = oi; }
                    }
                    if (tid == 0) finidx[p] = mi;
                }
                __syncthreads();
            }
        }
        __syncthreads();
    }

    // ---- epilogue: gather exact fp32 code row -> z_q, loss SSE ----
    // 2 threads per pixel, 32 channels each.
    {
        const int p  = tid & (PPB - 1);
        const int qq = tid >> 7;             // 0..1
        const int fi = finidx[p];
        const float4* crow4 = (const float4*)(cb + (size_t)fi * NC) + qq * 8;
        float sse = 0.f;
        #pragma unroll
        for (int j = 0; j < 8; ++j) {
            const float4 qv = crow4[j];
            const size_t c0 = (size_t)(qq * 32 + 4 * j) * HW + p;
            const float z0 = zbase[c0];
            const float z1 = zbase[c0 + HW];
            const float z2 = zbase[c0 + 2 * (size_t)HW];
            const float z3 = zbase[c0 + 3 * (size_t)HW];
            zqbase[c0]                  = qv.x;   // coalesced across threads
            zqbase[c0 + HW]             = qv.y;
            zqbase[c0 + 2 * (size_t)HW] = qv.z;
            zqbase[c0 + 3 * (size_t)HW] = qv.w;
            float t0 = qv.x - z0, t1 = qv.y - z1, t2 = qv.z - z2, t3 = qv.w - z3;
            sse = fmaf(t0, t0, sse);
            sse = fmaf(t1, t1, sse);
            sse = fmaf(t2, t2, sse);
            sse = fmaf(t3, t3, sse);
        }
        #pragma unroll
        for (int off = 32; off > 0; off >>= 1) sse += __shfl_down(sse, off);
        if ((tid & 63) == 0) redf[tid >> 6] = sse;
        __syncthreads();
        if (tid == 0)
            atomicAdd(loss_out, (redf[0] + redf[1] + redf[2] + redf[3]) *
                                (1.25f / (float)TOTAL));
    }
}

extern "C" void kernel_launch(void* const* d_in, const int* in_sizes, int n_in,
                              void* d_out, int out_size, void* d_ws, size_t ws_size,
                              hipStream_t stream) {
    const float* z  = (const float*)d_in[0];   // [32, 64, 64, 64] fp32
    const float* cb = (const float*)d_in[1];   // [1024, 64] fp32
    float* out      = (float*)d_out;           // z_q ++ loss
    float* zqp      = out;
    float* loss     = out + TOTAL;

    // ws: cnorm fp32[1024] | cb_hi bf16[1024*64] | cb_lo bf16[1024*64]
    float* cnorm          = (float*)d_ws;
    unsigned short* cb_hi = (unsigned short*)((char*)d_ws + 4096);
    unsigned short* cb_lo = (unsigned short*)((char*)d_ws + 4096 + NK * NC * 2);

    vq_prep_kernel<<<68, 256, 0, stream>>>(cb, cnorm, cb_hi, cb_lo, loss);
    vq_mfma_kernel<<<NPIX / PPB, 256, 0, stream>>>(z, cb, cb_hi, cb_lo, cnorm,
                                                   zqp, loss);
}